// Round 9
// baseline (323.290 us; speedup 1.0000x reference)
//
#include <hip/hip_runtime.h>
#include <math.h>

// ---------------------------------------------------------------------------
// EdgeCorrGNN: 4x GCNConv(+relu) + Linear(256,1).
// R9: gathers unrolled to 8 in-flight loads/lane + 32-bit addressing;
//     GEMM gets BN=128 tile (2x2 waves, 64x64/wave) halving A re-reads.
// ---------------------------------------------------------------------------

typedef _Float16 half8 __attribute__((ext_vector_type(8)));
typedef _Float16 half4_t __attribute__((ext_vector_type(4)));
typedef float f32x4 __attribute__((ext_vector_type(4)));

#define SCAN_CHUNK 2048           // elements per scan block (256 thr x 8)
#define DEG_SCALE 67108864.0f     // 2^26 fixed-point scale for weighted degree
#define DEG_MASK ((1ULL << 42) - 1)

__global__ __launch_bounds__(256) void k_init(unsigned long long* __restrict__ packed,
                                              int n) {
    int i = blockIdx.x * 256 + threadIdx.x;
    if (i < n) packed[i] = (1ULL << 26);   // deg = 1.0 (self-loop), cnt = 0
}

// one u64 atomic per edge; returned old count = slot within the dst row.
__global__ __launch_bounds__(256) void k_count_slot(const int* __restrict__ dst,
                                                    const float* __restrict__ w,
                                                    unsigned long long* __restrict__ packed,
                                                    int* __restrict__ slot, int e) {
    int i = blockIdx.x * 256 + threadIdx.x;
    if (i < e) {
        unsigned long long wf = (unsigned long long)(w[i] * DEG_SCALE + 0.5f);
        unsigned long long old = atomicAdd(&packed[dst[i]], (1ULL << 42) | wf);
        slot[i] = (int)(old >> 42);
    }
}

// unpack: dinv = rsqrt(deg), cnt for the scan.
__global__ __launch_bounds__(256) void k_dinv(const unsigned long long* __restrict__ packed,
                                              float* __restrict__ dinv,
                                              int* __restrict__ cnt, int n) {
    int i = blockIdx.x * 256 + threadIdx.x;
    if (i < n) {
        unsigned long long p = packed[i];
        float d = (float)((double)(p & DEG_MASK) * (1.0 / 67108864.0));
        dinv[i] = d > 0.0f ? rsqrtf(d) : 0.0f;
        cnt[i] = (int)(p >> 42);
    }
}

// --- parallel exclusive scan, 3 kernels -----------------------------------
__global__ __launch_bounds__(256) void k_scan_part(const int* __restrict__ cnt,
                                                   int* __restrict__ row_ptr,
                                                   int* __restrict__ blocksum, int n) {
    __shared__ int sp[256];
    int tid = threadIdx.x;
    int base = blockIdx.x * SCAN_CHUNK + tid * 8;
    int4 v0 = make_int4(0, 0, 0, 0), v1 = make_int4(0, 0, 0, 0);
    if (base < n) {
        v0 = *(const int4*)(cnt + base);
        v1 = *(const int4*)(cnt + base + 4);
    }
    int s = v0.x + v0.y + v0.z + v0.w + v1.x + v1.y + v1.z + v1.w;
    sp[tid] = s;
    __syncthreads();
    for (int d = 1; d < 256; d <<= 1) {
        int t = (tid >= d) ? sp[tid - d] : 0;
        __syncthreads();
        sp[tid] += t;
        __syncthreads();
    }
    int off = (tid == 0) ? 0 : sp[tid - 1];
    if (base < n) {
        int o[8] = {v0.x, v0.y, v0.z, v0.w, v1.x, v1.y, v1.z, v1.w};
        int run = off;
#pragma unroll
        for (int i = 0; i < 8; ++i) { int c = o[i]; o[i] = run; run += c; }
        *(int4*)(row_ptr + base)     = make_int4(o[0], o[1], o[2], o[3]);
        *(int4*)(row_ptr + base + 4) = make_int4(o[4], o[5], o[6], o[7]);
    }
    if (tid == 255) blocksum[blockIdx.x] = sp[255];
}

__global__ __launch_bounds__(64) void k_scan_mid(const int* __restrict__ blocksum,
                                                 int* __restrict__ blockoff, int nb) {
    int lane = threadIdx.x;
    int c = (lane < nb) ? blocksum[lane] : 0;
    int v = c;
    for (int d = 1; d < 64; d <<= 1) {
        int t = __shfl_up(v, d);
        if (lane >= d) v += t;
    }
    if (lane < nb) blockoff[lane] = v - c;
}

__global__ __launch_bounds__(256) void k_scan_add(int* __restrict__ row_ptr,
                                                  const int* __restrict__ blockoff,
                                                  int n, int total) {
    int tid = threadIdx.x;
    int base = blockIdx.x * SCAN_CHUNK + tid * 8;
    if (base < n) {
        int off = blockoff[blockIdx.x];
        int4 a = *(const int4*)(row_ptr + base);
        int4 b = *(const int4*)(row_ptr + base + 4);
        a.x += off; a.y += off; a.z += off; a.w += off;
        b.x += off; b.y += off; b.z += off; b.w += off;
        *(int4*)(row_ptr + base)     = a;
        *(int4*)(row_ptr + base + 4) = b;
    }
    if (blockIdx.x == 0 && tid == 0) row_ptr[n] = total;
}

// csr[row_ptr[dst] + slot] = (src, norm) -- pure scatter, no atomics.
__global__ __launch_bounds__(256) void k_fill(const int* __restrict__ src,
                                              const int* __restrict__ dst,
                                              const float* __restrict__ w,
                                              const float* __restrict__ dinv,
                                              const int* __restrict__ row_ptr,
                                              const int* __restrict__ slot,
                                              float2* __restrict__ csr, int e) {
    int i = blockIdx.x * 256 + threadIdx.x;
    if (i < e) {
        int d = dst[i], s = src[i];
        float nv = dinv[s] * w[i] * dinv[d];
        csr[row_ptr[d] + slot[i]] = make_float2(__int_as_float(s), nv);
    }
}

// ---------------------------------------------------------------------------
// fp16-MFMA GEMM: C[M,N] = A[M,K]@B[K,N] (+bias, relu). A fp32 or fp16;
// B/bias fp32; C fp16.  BM=128, BK=64, 4 waves.
// BN=64 : waves 4x1, 32x64 each (2x4 frags).
// BN=128: waves 2x2, 64x64 each (4x4 frags) -- halves A re-reads for wide N.
// ---------------------------------------------------------------------------
template <bool RELU, typename TA, int BN>
__global__ __launch_bounds__(256) void gemm_mfma(const TA* __restrict__ A,
                                                 const float* __restrict__ B,
                                                 const float* __restrict__ bias,
                                                 _Float16* __restrict__ C,
                                                 int M, int K, int N) {
    constexpr int PK = 72;
    constexpr int MR = (BN == 64) ? 2 : 4;   // 16-row frags per wave
    __shared__ _Float16 Asl[128 * PK];
    __shared__ _Float16 Bsl[BN * PK];

    int tid = threadIdx.x;
    int w = tid >> 6, l = tid & 63;
    int row0 = blockIdx.x * 128, col0 = blockIdx.y * BN;
    int lr = l & 15, lg = l >> 4;

    int wr, wc;
    if constexpr (BN == 64) { wr = w * 32; wc = 0; }
    else { wr = (w >> 1) * 64; wc = (w & 1) * 64; }

    int srow = tid >> 1;            // A staging: 0..127
    int skh = (tid & 1) * 32;       // half-row of 32 elems

    f32x4 acc[MR][4] = {};

    for (int k0 = 0; k0 < K; k0 += 64) {
        // --- stage A, 32 elems/thread ---
        const TA* ap = A + (size_t)(row0 + srow) * K + k0 + skh;
        bool aok = (row0 + srow) < M;
#pragma unroll
        for (int i = 0; i < 4; ++i) {
            half8 h;
            if constexpr (sizeof(TA) == 4) {
                float4 v0 = aok ? *(const float4*)((const float*)ap + i * 8 + 0)
                                : make_float4(0.f, 0.f, 0.f, 0.f);
                float4 v1 = aok ? *(const float4*)((const float*)ap + i * 8 + 4)
                                : make_float4(0.f, 0.f, 0.f, 0.f);
                h[0] = (_Float16)v0.x; h[1] = (_Float16)v0.y;
                h[2] = (_Float16)v0.z; h[3] = (_Float16)v0.w;
                h[4] = (_Float16)v1.x; h[5] = (_Float16)v1.y;
                h[6] = (_Float16)v1.z; h[7] = (_Float16)v1.w;
            } else {
                h = aok ? *(const half8*)((const _Float16*)ap + i * 8)
                        : half8{0, 0, 0, 0, 0, 0, 0, 0};
            }
            *(half8*)&Asl[srow * PK + skh + i * 8] = h;
        }
        // --- stage B transposed ([n][k]) ---
        if constexpr (BN == 64) {
            int bk = tid >> 4;          // 0..15
            int bn = (tid & 15) * 4;    // 0..60
#pragma unroll
            for (int r = 0; r < 4; ++r) {
                int kk = bk + r * 16;
                float4 wv = *(const float4*)(B + (size_t)(k0 + kk) * N + col0 + bn);
                Bsl[(bn + 0) * PK + kk] = (_Float16)wv.x;
                Bsl[(bn + 1) * PK + kk] = (_Float16)wv.y;
                Bsl[(bn + 2) * PK + kk] = (_Float16)wv.z;
                Bsl[(bn + 3) * PK + kk] = (_Float16)wv.w;
            }
        } else {
            int bk = tid >> 5;          // 0..7
            int bn = (tid & 31) * 4;    // 0..124
#pragma unroll
            for (int r = 0; r < 8; ++r) {
                int kk = bk + r * 8;
                float4 wv = *(const float4*)(B + (size_t)(k0 + kk) * N + col0 + bn);
                Bsl[(bn + 0) * PK + kk] = (_Float16)wv.x;
                Bsl[(bn + 1) * PK + kk] = (_Float16)wv.y;
                Bsl[(bn + 2) * PK + kk] = (_Float16)wv.z;
                Bsl[(bn + 3) * PK + kk] = (_Float16)wv.w;
            }
        }
        __syncthreads();

#pragma unroll
        for (int kr = 0; kr < 2; ++kr) {
            half8 af[MR], bf[4];
#pragma unroll
            for (int m = 0; m < MR; ++m)
                af[m] = *(half8*)&Asl[(wr + m * 16 + lr) * PK + kr * 32 + lg * 8];
#pragma unroll
            for (int n = 0; n < 4; ++n)
                bf[n] = *(half8*)&Bsl[(wc + n * 16 + lr) * PK + kr * 32 + lg * 8];
#pragma unroll
            for (int m = 0; m < MR; ++m)
#pragma unroll
                for (int n = 0; n < 4; ++n)
                    acc[m][n] = __builtin_amdgcn_mfma_f32_16x16x32_f16(
                        af[m], bf[n], acc[m][n], 0, 0, 0);
        }
        __syncthreads();
    }

#pragma unroll
    for (int m = 0; m < MR; ++m) {
#pragma unroll
        for (int r = 0; r < 4; ++r) {
            int row = row0 + wr + m * 16 + lg * 4 + r;
            if (row >= M) continue;
#pragma unroll
            for (int n = 0; n < 4; ++n) {
                int col = col0 + wc + n * 16 + lr;
                float v = acc[m][n][r];
                if (RELU) v = fmaxf(v + bias[col], 0.f);
                C[(size_t)row * N + col] = (_Float16)v;
            }
        }
    }
}

// ---------------------------------------------------------------------------
// Gather v2: one wave per node, half4 per lane, lane-group g processes edge
// e+g; UNR-step unroll -> UNR half4 loads in flight per lane.
// 32-bit H addressing (N*FO < 2^31 halves).
// ---------------------------------------------------------------------------
template <int FO, int UNR, bool BIASRELU>
__global__ __launch_bounds__(256) void k_gather2(const int* __restrict__ row_ptr,
                                                 const float2* __restrict__ csr,
                                                 const _Float16* __restrict__ H,
                                                 const float* __restrict__ dinv,
                                                 const float* __restrict__ b,
                                                 _Float16* __restrict__ O, int n) {
    constexpr int LPE = FO / 4;     // lanes per edge
    constexpr int GRP = 64 / LPE;   // edges processed in parallel
    int node = blockIdx.x * 4 + (threadIdx.x >> 6);
    int lane = threadIdx.x & 63;
    if (node >= n) return;
    int grp = lane / LPE;
    unsigned cols = (lane % LPE) * 4;

    float ax = 0.f, ay = 0.f, az = 0.f, aw = 0.f;
    int e0 = row_ptr[node], e1 = row_ptr[node + 1];

    for (int e = e0; e < e1; e += UNR * GRP) {
        float nv[UNR]; half4_t hv[UNR];
#pragma unroll
        for (int u = 0; u < UNR; ++u) {
            int er = e + u * GRP + grp;
            int eg = min(er, e1 - 1);
            float2 c = csr[eg];
            hv[u] = *(const half4_t*)(H + (unsigned)__float_as_int(c.x) * FO + cols);
            nv[u] = (er < e1) ? c.y : 0.f;
        }
#pragma unroll
        for (int u = 0; u < UNR; ++u) {
            ax += nv[u] * (float)hv[u][0];
            ay += nv[u] * (float)hv[u][1];
            az += nv[u] * (float)hv[u][2];
            aw += nv[u] * (float)hv[u][3];
        }
    }

#pragma unroll
    for (int off = LPE; off < 64; off <<= 1) {
        ax += __shfl_down(ax, off);
        ay += __shfl_down(ay, off);
        az += __shfl_down(az, off);
        aw += __shfl_down(aw, off);
    }

    if (lane < LPE) {
        float di = dinv[node];
        float s = di * di;
        half4_t hs = *(const half4_t*)(H + (unsigned)node * FO + cols);
        ax += s * (float)hs[0];
        ay += s * (float)hs[1];
        az += s * (float)hs[2];
        aw += s * (float)hs[3];
        if (BIASRELU) {
            float4 bv = *(const float4*)(b + cols);
            ax = fmaxf(ax + bv.x, 0.f);
            ay = fmaxf(ay + bv.y, 0.f);
            az = fmaxf(az + bv.z, 0.f);
            aw = fmaxf(aw + bv.w, 0.f);
        }
        half4_t o;
        o[0] = (_Float16)ax; o[1] = (_Float16)ay;
        o[2] = (_Float16)az; o[3] = (_Float16)aw;
        *(half4_t*)(O + (unsigned)node * FO + cols) = o;
    }
}

// ---------------------------------------------------------------------------
// Fused layer-4 gather + bias + relu + final Linear(256,1). One wave/node,
// unroll 8 (8 half4 loads in flight per lane).
// ---------------------------------------------------------------------------
__global__ __launch_bounds__(256) void k_gather_final2(const int* __restrict__ row_ptr,
                                                       const float2* __restrict__ csr,
                                                       const _Float16* __restrict__ H,
                                                       const float* __restrict__ dinv,
                                                       const float* __restrict__ b4,
                                                       const float* __restrict__ Wf,
                                                       const float* __restrict__ bf,
                                                       float* __restrict__ out, int n) {
    int node = blockIdx.x * 4 + (threadIdx.x >> 6);
    int lane = threadIdx.x & 63;
    if (node >= n) return;
    unsigned cols = lane * 4;

    float ax = 0.f, ay = 0.f, az = 0.f, aw = 0.f;
    int e0 = row_ptr[node], e1 = row_ptr[node + 1];

    for (int e = e0; e < e1; e += 8) {
        float nv[8]; half4_t hv[8];
#pragma unroll
        for (int u = 0; u < 8; ++u) {
            int er = e + u;
            int eg = min(er, e1 - 1);
            float2 c = csr[eg];
            hv[u] = *(const half4_t*)(H + (unsigned)__float_as_int(c.x) * 256 + cols);
            nv[u] = (er < e1) ? c.y : 0.f;
        }
#pragma unroll
        for (int u = 0; u < 8; ++u) {
            ax += nv[u] * (float)hv[u][0];
            ay += nv[u] * (float)hv[u][1];
            az += nv[u] * (float)hv[u][2];
            aw += nv[u] * (float)hv[u][3];
        }
    }

    float di = dinv[node];
    float s = di * di;
    half4_t hs = *(const half4_t*)(H + (unsigned)node * 256 + cols);
    float4 bv = *(const float4*)(b4 + cols);
    float4 wv = *(const float4*)(Wf + cols);
    float v = fmaxf(ax + s * (float)hs[0] + bv.x, 0.f) * wv.x
            + fmaxf(ay + s * (float)hs[1] + bv.y, 0.f) * wv.y
            + fmaxf(az + s * (float)hs[2] + bv.z, 0.f) * wv.z
            + fmaxf(aw + s * (float)hs[3] + bv.w, 0.f) * wv.w;
#pragma unroll
    for (int off = 32; off > 0; off >>= 1) v += __shfl_down(v, off);
    if (lane == 0) out[node] = v + bf[0];
}

// ---------------------------------------------------------------------------

extern "C" void kernel_launch(void* const* d_in, const int* in_sizes, int n_in,
                              void* d_out, int out_size, void* d_ws, size_t ws_size,
                              hipStream_t stream) {
    const float* x    = (const float*)d_in[0];
    const int*   eidx = (const int*)d_in[1];
    const float* eatt = (const float*)d_in[2];
    const float* W1 = (const float*)d_in[3];
    const float* b1 = (const float*)d_in[4];
    const float* W2 = (const float*)d_in[5];
    const float* b2 = (const float*)d_in[6];
    const float* W3 = (const float*)d_in[7];
    const float* b3 = (const float*)d_in[8];
    const float* W4 = (const float*)d_in[9];
    const float* b4 = (const float*)d_in[10];
    const float* Wf = (const float*)d_in[11];
    const float* bf = (const float*)d_in[12];

    const int NN = in_sizes[0] / 128;   // 50000
    const int NE = in_sizes[2];         // 800000
    const int* src = eidx;              // edge_index[0]
    const int* dst = eidx + NE;         // edge_index[1]

    // workspace layout (u64 array first for 8B alignment)
    const int Na = (NN + 64) & ~63;
    unsigned long long* packed = (unsigned long long*)d_ws;   // N u64
    float* dinv    = (float*)(packed + Na);     // N floats
    int*   row_ptr = (int*)(dinv + Na);         // N+1 ints
    int*   cnt     = row_ptr + Na;              // N ints
    int*   bsum    = cnt + Na;                  // 64 ints
    int*   boff    = bsum + 64;                 // 64 ints
    int*   slot    = boff + 64;                 // E ints
    float2* csr    = (float2*)(slot + ((NE + 1) & ~1));   // E float2
    _Float16* bufA = (_Float16*)(csr + NE);     // N*256 halves
    _Float16* bufB = bufA + (size_t)NN * 256;   // N*256 halves

    const int nscan = (NN + SCAN_CHUNK - 1) / SCAN_CHUNK;   // 25

    // --- graph preprocessing ---
    k_init<<<(NN + 255) / 256, 256, 0, stream>>>(packed, NN);
    k_count_slot<<<(NE + 255) / 256, 256, 0, stream>>>(dst, eatt, packed, slot, NE);
    k_dinv<<<(NN + 255) / 256, 256, 0, stream>>>(packed, dinv, cnt, NN);
    k_scan_part<<<nscan, 256, 0, stream>>>(cnt, row_ptr, bsum, NN);
    k_scan_mid<<<1, 64, 0, stream>>>(bsum, boff, nscan);
    k_scan_add<<<nscan, 256, 0, stream>>>(row_ptr, boff, NN, NE);
    k_fill<<<(NE + 255) / 256, 256, 0, stream>>>(src, dst, eatt, dinv, row_ptr, slot, csr, NE);

    int gw = (NN + 3) / 4;   // one wave per node, 4 waves per block
    int gx = (NN + 127) / 128;

    // --- L1 (128->64), aggregate AFTER: H1 = x@W1; h1 = relu(gather(H1)+b1)
    gemm_mfma<false, float, 64><<<dim3(gx, 1), 256, 0, stream>>>(x, W1, nullptr, bufB, NN, 128, 64);
    k_gather2<64, 4, true><<<gw, 256, 0, stream>>>(row_ptr, csr, bufB, dinv, b1, bufA, NN);

    // --- L2 (64->128), aggregate BEFORE: g2 = gather(h1); h2 = relu(g2@W2+b2)
    k_gather2<64, 4, false><<<gw, 256, 0, stream>>>(row_ptr, csr, bufA, dinv, nullptr, bufB, NN);
    gemm_mfma<true, _Float16, 128><<<dim3(gx, 1), 256, 0, stream>>>(bufB, W2, b2, bufA, NN, 64, 128);

    // --- L3 (128->256), aggregate BEFORE: g3 = gather(h2); h3 = relu(g3@W3+b3)
    k_gather2<128, 8, false><<<gw, 256, 0, stream>>>(row_ptr, csr, bufA, dinv, nullptr, bufB, NN);
    gemm_mfma<true, _Float16, 128><<<dim3(gx, 2), 256, 0, stream>>>(bufB, W3, b3, bufA, NN, 128, 256);

    // --- L4 (256->256) aggregate AFTER + fused final dot
    gemm_mfma<false, _Float16, 128><<<dim3(gx, 2), 256, 0, stream>>>(bufA, W4, nullptr, bufB, NN, 256, 256);
    k_gather_final2<<<gw, 256, 0, stream>>>(row_ptr, csr, bufB, dinv, b4, Wf, bf,
                                            (float*)d_out, NN);
}

// Round 10
// 291.759 us; speedup vs baseline: 1.1081x; 1.1081x over previous
//
#include <hip/hip_runtime.h>
#include <math.h>

// ---------------------------------------------------------------------------
// EdgeCorrGNN: 4x GCNConv(+relu) + Linear(256,1).
// R10: R8 baseline (gathers unroll-4, GEMM BN=64) + fp16 pre-converted
// weights + XCD-aware col-major block decode for N=256 GEMMs.
// ---------------------------------------------------------------------------

typedef _Float16 half8 __attribute__((ext_vector_type(8)));
typedef _Float16 half4_t __attribute__((ext_vector_type(4)));
typedef float f32x4 __attribute__((ext_vector_type(4)));

#define SCAN_CHUNK 2048           // elements per scan block (256 thr x 8)
#define DEG_SCALE 67108864.0f     // 2^26 fixed-point scale for weighted degree
#define DEG_MASK ((1ULL << 42) - 1)

__global__ __launch_bounds__(256) void k_init(unsigned long long* __restrict__ packed,
                                              int n) {
    int i = blockIdx.x * 256 + threadIdx.x;
    if (i < n) packed[i] = (1ULL << 26);   // deg = 1.0 (self-loop), cnt = 0
}

// one u64 atomic per edge; returned old count = slot within the dst row.
__global__ __launch_bounds__(256) void k_count_slot(const int* __restrict__ dst,
                                                    const float* __restrict__ w,
                                                    unsigned long long* __restrict__ packed,
                                                    int* __restrict__ slot, int e) {
    int i = blockIdx.x * 256 + threadIdx.x;
    if (i < e) {
        unsigned long long wf = (unsigned long long)(w[i] * DEG_SCALE + 0.5f);
        unsigned long long old = atomicAdd(&packed[dst[i]], (1ULL << 42) | wf);
        slot[i] = (int)(old >> 42);
    }
}

// unpack: dinv = rsqrt(deg), cnt for the scan.
__global__ __launch_bounds__(256) void k_dinv(const unsigned long long* __restrict__ packed,
                                              float* __restrict__ dinv,
                                              int* __restrict__ cnt, int n) {
    int i = blockIdx.x * 256 + threadIdx.x;
    if (i < n) {
        unsigned long long p = packed[i];
        float d = (float)((double)(p & DEG_MASK) * (1.0 / 67108864.0));
        dinv[i] = d > 0.0f ? rsqrtf(d) : 0.0f;
        cnt[i] = (int)(p >> 42);
    }
}

// convert W1..W4 (fp32) into one contiguous fp16 array.
// sizes: 8192, 8192, 32768, 65536 (cum 0, 8192, 16384, 49152, 114688).
__global__ __launch_bounds__(256) void k_cvtw(const float* __restrict__ W1,
                                              const float* __restrict__ W2,
                                              const float* __restrict__ W3,
                                              const float* __restrict__ W4,
                                              _Float16* __restrict__ out) {
    int i = blockIdx.x * 256 + threadIdx.x;
    if (i >= 114688) return;
    const float* src; int off;
    if (i < 8192)       { src = W1; off = 0; }
    else if (i < 16384) { src = W2; off = 8192; }
    else if (i < 49152) { src = W3; off = 16384; }
    else                { src = W4; off = 49152; }
    out[i] = (_Float16)src[i - off];
}

// --- parallel exclusive scan, 3 kernels -----------------------------------
__global__ __launch_bounds__(256) void k_scan_part(const int* __restrict__ cnt,
                                                   int* __restrict__ row_ptr,
                                                   int* __restrict__ blocksum, int n) {
    __shared__ int sp[256];
    int tid = threadIdx.x;
    int base = blockIdx.x * SCAN_CHUNK + tid * 8;
    int4 v0 = make_int4(0, 0, 0, 0), v1 = make_int4(0, 0, 0, 0);
    if (base < n) {
        v0 = *(const int4*)(cnt + base);
        v1 = *(const int4*)(cnt + base + 4);
    }
    int s = v0.x + v0.y + v0.z + v0.w + v1.x + v1.y + v1.z + v1.w;
    sp[tid] = s;
    __syncthreads();
    for (int d = 1; d < 256; d <<= 1) {
        int t = (tid >= d) ? sp[tid - d] : 0;
        __syncthreads();
        sp[tid] += t;
        __syncthreads();
    }
    int off = (tid == 0) ? 0 : sp[tid - 1];
    if (base < n) {
        int o[8] = {v0.x, v0.y, v0.z, v0.w, v1.x, v1.y, v1.z, v1.w};
        int run = off;
#pragma unroll
        for (int i = 0; i < 8; ++i) { int c = o[i]; o[i] = run; run += c; }
        *(int4*)(row_ptr + base)     = make_int4(o[0], o[1], o[2], o[3]);
        *(int4*)(row_ptr + base + 4) = make_int4(o[4], o[5], o[6], o[7]);
    }
    if (tid == 255) blocksum[blockIdx.x] = sp[255];
}

__global__ __launch_bounds__(64) void k_scan_mid(const int* __restrict__ blocksum,
                                                 int* __restrict__ blockoff, int nb) {
    int lane = threadIdx.x;
    int c = (lane < nb) ? blocksum[lane] : 0;
    int v = c;
    for (int d = 1; d < 64; d <<= 1) {
        int t = __shfl_up(v, d);
        if (lane >= d) v += t;
    }
    if (lane < nb) blockoff[lane] = v - c;
}

__global__ __launch_bounds__(256) void k_scan_add(int* __restrict__ row_ptr,
                                                  const int* __restrict__ blockoff,
                                                  int n, int total) {
    int tid = threadIdx.x;
    int base = blockIdx.x * SCAN_CHUNK + tid * 8;
    if (base < n) {
        int off = blockoff[blockIdx.x];
        int4 a = *(const int4*)(row_ptr + base);
        int4 b = *(const int4*)(row_ptr + base + 4);
        a.x += off; a.y += off; a.z += off; a.w += off;
        b.x += off; b.y += off; b.z += off; b.w += off;
        *(int4*)(row_ptr + base)     = a;
        *(int4*)(row_ptr + base + 4) = b;
    }
    if (blockIdx.x == 0 && tid == 0) row_ptr[n] = total;
}

// csr[row_ptr[dst] + slot] = (src, norm) -- pure scatter, no atomics.
__global__ __launch_bounds__(256) void k_fill(const int* __restrict__ src,
                                              const int* __restrict__ dst,
                                              const float* __restrict__ w,
                                              const float* __restrict__ dinv,
                                              const int* __restrict__ row_ptr,
                                              const int* __restrict__ slot,
                                              float2* __restrict__ csr, int e) {
    int i = blockIdx.x * 256 + threadIdx.x;
    if (i < e) {
        int d = dst[i], s = src[i];
        float nv = dinv[s] * w[i] * dinv[d];
        csr[row_ptr[d] + slot[i]] = make_float2(__int_as_float(s), nv);
    }
}

// ---------------------------------------------------------------------------
// fp16-MFMA GEMM: C[M,N] = A[M,K]@B16[K,N] (+bias, relu). A fp32 or fp16;
// B fp16 (pre-converted), bias fp32, C fp16. BM=128, BN=64, BK=64;
// 4 waves x (32rows x 64cols).
// XCD4: 1-D grid, bid -> (xcd=bid&7, cb=(bid>>3)&3, rb=xcd+8*(bid>>5)) so a
// row-tile's 4 col-blocks land on one XCD's L2 (A fetched once per XCD).
// ---------------------------------------------------------------------------
template <bool RELU, typename TA, bool XCD4>
__global__ __launch_bounds__(256) void gemm_mfma(const TA* __restrict__ A,
                                                 const _Float16* __restrict__ B,
                                                 const float* __restrict__ bias,
                                                 _Float16* __restrict__ C,
                                                 int M, int K, int N) {
    constexpr int PK = 72;
    __shared__ _Float16 Asl[128 * PK];
    __shared__ _Float16 Bsl[64 * PK];

    int tid = threadIdx.x;
    int w = tid >> 6, l = tid & 63;
    int row0, col0;
    if constexpr (XCD4) {
        int bid = blockIdx.x;
        int xcd = bid & 7;
        int cb = (bid >> 3) & 3;
        int rb = xcd + 8 * (bid >> 5);
        row0 = rb * 128;
        col0 = cb * 64;
    } else {
        row0 = blockIdx.x * 128;
        col0 = blockIdx.y * 64;
    }
    int wr = w * 32;
    int lr = l & 15, lg = l >> 4;

    int srow = tid >> 1;            // A staging: 0..127
    int skh = (tid & 1) * 32;       // half-row of 32 elems
    int bk = tid >> 4;              // B staging: k 0..15 (+16r)
    int bn = (tid & 15) * 4;        // n group of 4

    f32x4 acc[2][4] = {};

    for (int k0 = 0; k0 < K; k0 += 64) {
        // --- stage A, 32 elems/thread ---
        const TA* ap = A + (size_t)(row0 + srow) * K + k0 + skh;
        bool aok = (row0 + srow) < M;
#pragma unroll
        for (int i = 0; i < 4; ++i) {
            half8 h;
            if constexpr (sizeof(TA) == 4) {
                float4 v0 = aok ? *(const float4*)((const float*)ap + i * 8 + 0)
                                : make_float4(0.f, 0.f, 0.f, 0.f);
                float4 v1 = aok ? *(const float4*)((const float*)ap + i * 8 + 4)
                                : make_float4(0.f, 0.f, 0.f, 0.f);
                h[0] = (_Float16)v0.x; h[1] = (_Float16)v0.y;
                h[2] = (_Float16)v0.z; h[3] = (_Float16)v0.w;
                h[4] = (_Float16)v1.x; h[5] = (_Float16)v1.y;
                h[6] = (_Float16)v1.z; h[7] = (_Float16)v1.w;
            } else {
                h = aok ? *(const half8*)((const _Float16*)ap + i * 8)
                        : half8{0, 0, 0, 0, 0, 0, 0, 0};
            }
            *(half8*)&Asl[srow * PK + skh + i * 8] = h;
        }
        // --- stage B transposed ([n][k]), fp16 source ---
#pragma unroll
        for (int r = 0; r < 4; ++r) {
            int kk = bk + r * 16;
            half4_t wv = *(const half4_t*)(B + (size_t)(k0 + kk) * N + col0 + bn);
            Bsl[(bn + 0) * PK + kk] = wv[0];
            Bsl[(bn + 1) * PK + kk] = wv[1];
            Bsl[(bn + 2) * PK + kk] = wv[2];
            Bsl[(bn + 3) * PK + kk] = wv[3];
        }
        __syncthreads();

#pragma unroll
        for (int kr = 0; kr < 2; ++kr) {
            half8 af[2], bf[4];
#pragma unroll
            for (int m = 0; m < 2; ++m)
                af[m] = *(half8*)&Asl[(wr + m * 16 + lr) * PK + kr * 32 + lg * 8];
#pragma unroll
            for (int n = 0; n < 4; ++n)
                bf[n] = *(half8*)&Bsl[(n * 16 + lr) * PK + kr * 32 + lg * 8];
#pragma unroll
            for (int m = 0; m < 2; ++m)
#pragma unroll
                for (int n = 0; n < 4; ++n)
                    acc[m][n] = __builtin_amdgcn_mfma_f32_16x16x32_f16(
                        af[m], bf[n], acc[m][n], 0, 0, 0);
        }
        __syncthreads();
    }

#pragma unroll
    for (int m = 0; m < 2; ++m) {
#pragma unroll
        for (int r = 0; r < 4; ++r) {
            int row = row0 + wr + m * 16 + lg * 4 + r;
            if (row >= M) continue;
#pragma unroll
            for (int n = 0; n < 4; ++n) {
                int col = col0 + n * 16 + lr;
                float v = acc[m][n][r];
                if (RELU) v = fmaxf(v + bias[col], 0.f);
                C[(size_t)row * N + col] = (_Float16)v;
            }
        }
    }
}

// ---------------------------------------------------------------------------
// Gather v2 (R8): one wave per node, half4 per lane, lane-groups process GRP
// edges concurrently, 4-step unroll.
// ---------------------------------------------------------------------------
template <int FO, bool BIASRELU>
__global__ __launch_bounds__(256) void k_gather2(const int* __restrict__ row_ptr,
                                                 const float2* __restrict__ csr,
                                                 const _Float16* __restrict__ H,
                                                 const float* __restrict__ dinv,
                                                 const float* __restrict__ b,
                                                 _Float16* __restrict__ O, int n) {
    constexpr int LPE = FO / 4;     // lanes per edge
    constexpr int GRP = 64 / LPE;   // edges processed in parallel
    int node = blockIdx.x * 4 + (threadIdx.x >> 6);
    int lane = threadIdx.x & 63;
    if (node >= n) return;
    int grp = lane / LPE;
    int cols = (lane % LPE) * 4;

    float ax = 0.f, ay = 0.f, az = 0.f, aw = 0.f;
    int e0 = row_ptr[node], e1 = row_ptr[node + 1];

    for (int e = e0; e < e1; e += 4 * GRP) {
        float nv[4]; half4_t hv[4];
#pragma unroll
        for (int u = 0; u < 4; ++u) {
            int er = e + u * GRP + grp;
            int eg = min(er, e1 - 1);
            float2 c = csr[eg];
            hv[u] = *(const half4_t*)(H + (size_t)__float_as_int(c.x) * FO + cols);
            nv[u] = (er < e1) ? c.y : 0.f;
        }
#pragma unroll
        for (int u = 0; u < 4; ++u) {
            ax += nv[u] * (float)hv[u][0];
            ay += nv[u] * (float)hv[u][1];
            az += nv[u] * (float)hv[u][2];
            aw += nv[u] * (float)hv[u][3];
        }
    }

#pragma unroll
    for (int off = LPE; off < 64; off <<= 1) {
        ax += __shfl_down(ax, off);
        ay += __shfl_down(ay, off);
        az += __shfl_down(az, off);
        aw += __shfl_down(aw, off);
    }

    if (lane < LPE) {
        float di = dinv[node];
        float s = di * di;
        half4_t hs = *(const half4_t*)(H + (size_t)node * FO + cols);
        ax += s * (float)hs[0];
        ay += s * (float)hs[1];
        az += s * (float)hs[2];
        aw += s * (float)hs[3];
        if (BIASRELU) {
            float4 bv = *(const float4*)(b + cols);
            ax = fmaxf(ax + bv.x, 0.f);
            ay = fmaxf(ay + bv.y, 0.f);
            az = fmaxf(az + bv.z, 0.f);
            aw = fmaxf(aw + bv.w, 0.f);
        }
        half4_t o;
        o[0] = (_Float16)ax; o[1] = (_Float16)ay;
        o[2] = (_Float16)az; o[3] = (_Float16)aw;
        *(half4_t*)(O + (size_t)node * FO + cols) = o;
    }
}

// ---------------------------------------------------------------------------
// Fused layer-4 gather + bias + relu + final Linear(256,1). One wave/node,
// unroll 4 (R8).
// ---------------------------------------------------------------------------
__global__ __launch_bounds__(256) void k_gather_final2(const int* __restrict__ row_ptr,
                                                       const float2* __restrict__ csr,
                                                       const _Float16* __restrict__ H,
                                                       const float* __restrict__ dinv,
                                                       const float* __restrict__ b4,
                                                       const float* __restrict__ Wf,
                                                       const float* __restrict__ bf,
                                                       float* __restrict__ out, int n) {
    int node = blockIdx.x * 4 + (threadIdx.x >> 6);
    int lane = threadIdx.x & 63;
    if (node >= n) return;
    int cols = lane * 4;

    float ax = 0.f, ay = 0.f, az = 0.f, aw = 0.f;
    int e0 = row_ptr[node], e1 = row_ptr[node + 1];

    for (int e = e0; e < e1; e += 4) {
        float nv[4]; half4_t hv[4];
#pragma unroll
        for (int u = 0; u < 4; ++u) {
            int er = e + u;
            int eg = min(er, e1 - 1);
            float2 c = csr[eg];
            hv[u] = *(const half4_t*)(H + (size_t)__float_as_int(c.x) * 256 + cols);
            nv[u] = (er < e1) ? c.y : 0.f;
        }
#pragma unroll
        for (int u = 0; u < 4; ++u) {
            ax += nv[u] * (float)hv[u][0];
            ay += nv[u] * (float)hv[u][1];
            az += nv[u] * (float)hv[u][2];
            aw += nv[u] * (float)hv[u][3];
        }
    }

    float di = dinv[node];
    float s = di * di;
    half4_t hs = *(const half4_t*)(H + (size_t)node * 256 + cols);
    float4 bv = *(const float4*)(b4 + cols);
    float4 wv = *(const float4*)(Wf + cols);
    float v = fmaxf(ax + s * (float)hs[0] + bv.x, 0.f) * wv.x
            + fmaxf(ay + s * (float)hs[1] + bv.y, 0.f) * wv.y
            + fmaxf(az + s * (float)hs[2] + bv.z, 0.f) * wv.z
            + fmaxf(aw + s * (float)hs[3] + bv.w, 0.f) * wv.w;
#pragma unroll
    for (int off = 32; off > 0; off >>= 1) v += __shfl_down(v, off);
    if (lane == 0) out[node] = v + bf[0];
}

// ---------------------------------------------------------------------------

extern "C" void kernel_launch(void* const* d_in, const int* in_sizes, int n_in,
                              void* d_out, int out_size, void* d_ws, size_t ws_size,
                              hipStream_t stream) {
    const float* x    = (const float*)d_in[0];
    const int*   eidx = (const int*)d_in[1];
    const float* eatt = (const float*)d_in[2];
    const float* W1 = (const float*)d_in[3];
    const float* b1 = (const float*)d_in[4];
    const float* W2 = (const float*)d_in[5];
    const float* b2 = (const float*)d_in[6];
    const float* W3 = (const float*)d_in[7];
    const float* b3 = (const float*)d_in[8];
    const float* W4 = (const float*)d_in[9];
    const float* b4 = (const float*)d_in[10];
    const float* Wf = (const float*)d_in[11];
    const float* bf = (const float*)d_in[12];

    const int NN = in_sizes[0] / 128;   // 50000
    const int NE = in_sizes[2];         // 800000
    const int* src = eidx;              // edge_index[0]
    const int* dst = eidx + NE;         // edge_index[1]

    // workspace layout (u64 array first for 8B alignment)
    const int Na = (NN + 64) & ~63;
    unsigned long long* packed = (unsigned long long*)d_ws;   // N u64
    float* dinv    = (float*)(packed + Na);     // N floats
    int*   row_ptr = (int*)(dinv + Na);         // N+1 ints
    int*   cnt     = row_ptr + Na;              // N ints
    int*   bsum    = cnt + Na;                  // 64 ints
    int*   boff    = bsum + 64;                 // 64 ints
    _Float16* wf16 = (_Float16*)(boff + 64);    // 114688 halves (W1..W4 fp16)
    int*   slot    = (int*)(wf16 + 114688);     // E ints
    float2* csr    = (float2*)(slot + ((NE + 1) & ~1));   // E float2
    _Float16* bufA = (_Float16*)(csr + NE);     // N*256 halves
    _Float16* bufB = bufA + (size_t)NN * 256;   // N*256 halves

    const _Float16* W1h = wf16;
    const _Float16* W2h = wf16 + 8192;
    const _Float16* W3h = wf16 + 16384;
    const _Float16* W4h = wf16 + 49152;

    const int nscan = (NN + SCAN_CHUNK - 1) / SCAN_CHUNK;   // 25

    // --- weight conversion + graph preprocessing ---
    k_cvtw<<<448, 256, 0, stream>>>(W1, W2, W3, W4, wf16);
    k_init<<<(NN + 255) / 256, 256, 0, stream>>>(packed, NN);
    k_count_slot<<<(NE + 255) / 256, 256, 0, stream>>>(dst, eatt, packed, slot, NE);
    k_dinv<<<(NN + 255) / 256, 256, 0, stream>>>(packed, dinv, cnt, NN);
    k_scan_part<<<nscan, 256, 0, stream>>>(cnt, row_ptr, bsum, NN);
    k_scan_mid<<<1, 64, 0, stream>>>(bsum, boff, nscan);
    k_scan_add<<<nscan, 256, 0, stream>>>(row_ptr, boff, NN, NE);
    k_fill<<<(NE + 255) / 256, 256, 0, stream>>>(src, dst, eatt, dinv, row_ptr, slot, csr, NE);

    int gw = (NN + 3) / 4;               // one wave per node, 4 waves per block
    int gx = (NN + 127) / 128;           // 391 row tiles
    int gx8 = ((gx + 7) & ~7);           // 392, padded to multiple of 8
    int gxcd = gx8 * 4;                  // 1-D grid for XCD4 decode (N=256)

    // --- L1 (128->64), aggregate AFTER: H1 = x@W1; h1 = relu(gather(H1)+b1)
    gemm_mfma<false, float, false><<<dim3(gx, 1), 256, 0, stream>>>(x, W1h, nullptr, bufB, NN, 128, 64);
    k_gather2<64, true><<<gw, 256, 0, stream>>>(row_ptr, csr, bufB, dinv, b1, bufA, NN);

    // --- L2 (64->128), aggregate BEFORE: g2 = gather(h1); h2 = relu(g2@W2+b2)
    k_gather2<64, false><<<gw, 256, 0, stream>>>(row_ptr, csr, bufA, dinv, nullptr, bufB, NN);
    gemm_mfma<true, _Float16, false><<<dim3(gx, 2), 256, 0, stream>>>(bufB, W2h, b2, bufA, NN, 64, 128);

    // --- L3 (128->256), aggregate BEFORE: g3 = gather(h2); h3 = relu(g3@W3+b3)
    k_gather2<128, false><<<gw, 256, 0, stream>>>(row_ptr, csr, bufA, dinv, nullptr, bufB, NN);
    gemm_mfma<true, _Float16, true><<<dim3(gxcd, 1), 256, 0, stream>>>(bufB, W3h, b3, bufA, NN, 128, 256);

    // --- L4 (256->256) aggregate AFTER + fused final dot
    gemm_mfma<false, _Float16, true><<<dim3(gxcd, 1), 256, 0, stream>>>(bufA, W4h, nullptr, bufB, NN, 256, 256);
    k_gather_final2<<<gw, 256, 0, stream>>>(row_ptr, csr, bufB, dinv, b4, Wf, bf,
                                            (float*)d_out, NN);
}